// Round 6
// baseline (117.714 us; speedup 1.0000x reference)
//
#include <hip/hip_runtime.h>

// out[b,i,j] = conv3x3_valid(inp, c*k)[b,i,j]
// c = vt(I=1) from the LIF scan (linear in I; spike/clamp provably inactive
// since I < 9 < 14 for all 1000 steps). c folded into the taps.
//
// R5 (single-strip LDS staging) ~30us: load phase exposed once per block.
// R6: double-buffered strips. Each block owns a 32-row slab = 4 strips of 8
// output rows. While strip s is computed from LDS buffer s&1, strip s+1 is
// already in flight into the other buffer via async global_load_lds width=16
// (issued right after the barrier -> overlaps all of compute+stores).
// LDS = 2 x 10 x 512 x 4 = 40960 B exactly -> 4 blocks/CU; grid 16x64 = 1024
// blocks -> whole grid co-resident (4 blocks/CU x 256 CU).

#define SROWS  8
#define NSTRIP 4
#define TFLOATS (10 * 512)            // 5120 floats = 20480 B per buffer

__device__ static inline void async_copy16(const float* gsrc, float* ldst) {
    __builtin_amdgcn_global_load_lds(
        (const __attribute__((address_space(1))) void*)gsrc,
        (__attribute__((address_space(3))) void*)ldst, 16, 0, 0);
}

__global__ __launch_bounds__(256) void snn_conv_dbuf_kernel(
    const float* __restrict__ inp, const float* __restrict__ kw,
    float* __restrict__ out, float c)
{
    __shared__ float tile[2][TFLOATS];

    const int tid   = threadIdx.x;
    const int b     = blockIdx.y;
    const int slab0 = blockIdx.x * (NSTRIP * SROWS);   // first output row of slab

    const float* gbase = inp + (size_t)b * 262144;     // 512*512

    // stage strip 0 into buffer 0 (async, no VGPR dependency)
    {
        const int gf0 = slab0 * 512;
#pragma unroll
        for (int rnd = 0; rnd < 5; ++rnd) {
            const int fo = (rnd * 256 + tid) * 4;
            async_copy16(gbase + min(gf0 + fo, 262140), &tile[0][fo]);
        }
    }

    // taps (uniform -> SGPRs), c folded; overlaps staging
    const float k00 = kw[0]*c, k01 = kw[1]*c, k02 = kw[2]*c;
    const float k10 = kw[3]*c, k11 = kw[4]*c, k12 = kw[5]*c;
    const float k20 = kw[6]*c, k21 = kw[7]*c, k22 = kw[8]*c;

    const int tp = tid & 127;                 // column group: cols 4tp..4tp+3
    const int ty = tid >> 7;                  // row group 0/1
    const int j  = tp << 2;
    const int r0 = ty << 2;                   // strip-relative first out row
    const bool main_lane = (tp < 127);
    const int hoff = main_lane ? 4 : 0;       // clamped halo offset (tp==127:
                                              // re-reads j..j+1, values unused)
    float* obase = out + (size_t)b * 260100;  // 510*510

    float x0, x1, x2, x3, x4, x5;
#define LOADX(tb, ir)                                               \
    {   const float* _p = (tb) + (ir) * 512 + j;                    \
        float4 _a = *(const float4*)_p;                             \
        float2 _b = *(const float2*)(_p + hoff);                    \
        x0=_a.x; x1=_a.y; x2=_a.z; x3=_a.w; x4=_b.x; x5=_b.y; }

#pragma unroll
    for (int s = 0; s < NSTRIP; ++s) {
        __syncthreads();   // strip-s loads landed; buffer s&1 free of readers

        if (s + 1 < NSTRIP) {               // prefetch strip s+1, flies during compute
            const int gf0 = (slab0 + (s + 1) * SROWS) * 512;
#pragma unroll
            for (int rnd = 0; rnd < 5; ++rnd) {
                const int fo = (rnd * 256 + tid) * 4;
                async_copy16(gbase + min(gf0 + fo, 262140), &tile[(s + 1) & 1][fo]);
            }
        }

        const float* tb = tile[s & 1];
        float a2[4], a1[4], o[4];
        LOADX(tb, r0);
        a2[0] = k00*x0 + k01*x1 + k02*x2;
        a2[1] = k00*x1 + k01*x2 + k02*x3;
        a2[2] = k00*x2 + k01*x3 + k02*x4;
        a2[3] = k00*x3 + k01*x4 + k02*x5;
        LOADX(tb, r0 + 1);
        a1[0] = k00*x0 + k01*x1 + k02*x2;  a2[0] += k10*x0 + k11*x1 + k12*x2;
        a1[1] = k00*x1 + k01*x2 + k02*x3;  a2[1] += k10*x1 + k11*x2 + k12*x3;
        a1[2] = k00*x2 + k01*x3 + k02*x4;  a2[2] += k10*x2 + k11*x3 + k12*x4;
        a1[3] = k00*x3 + k01*x4 + k02*x5;  a2[3] += k10*x3 + k11*x4 + k12*x5;

        const int ob0 = slab0 + s * SROWS + r0;   // parity(ob0)==0
#pragma unroll
        for (int r = 0; r < 4; ++r) {
            LOADX(tb, r0 + r + 2);
            o[0] = a2[0] + k20*x0 + k21*x1 + k22*x2;
            o[1] = a2[1] + k20*x1 + k21*x2 + k22*x3;
            o[2] = a2[2] + k20*x2 + k21*x3 + k22*x4;
            o[3] = a2[3] + k20*x3 + k21*x4 + k22*x5;

            const int orow = ob0 + r;             // parity(orow)==parity(r)
            if (orow < 510) {
                float* q = obase + (size_t)orow * 510 + j;
                if ((r & 1) == 0) {               // byte offset % 16 == 0
                    if (main_lane) *(float4*)q = make_float4(o[0], o[1], o[2], o[3]);
                    else           *(float2*)q = make_float2(o[0], o[1]);
                } else {                          // byte offset % 16 == 8
                    *(float2*)q = make_float2(o[0], o[1]);
                    if (main_lane) *(float2*)(q + 2) = make_float2(o[2], o[3]);
                }
            }
            a2[0] = a1[0] + k10*x0 + k11*x1 + k12*x2;
            a2[1] = a1[1] + k10*x1 + k11*x2 + k12*x3;
            a2[2] = a1[2] + k10*x2 + k11*x3 + k12*x4;
            a2[3] = a1[3] + k10*x3 + k11*x4 + k12*x5;
            a1[0] = k00*x0 + k01*x1 + k02*x2;
            a1[1] = k00*x1 + k01*x2 + k02*x3;
            a1[2] = k00*x2 + k01*x3 + k02*x4;
            a1[3] = k00*x3 + k01*x4 + k02*x5;
        }
    }
#undef LOADX
}

extern "C" void kernel_launch(void* const* d_in, const int* in_sizes, int n_in,
                              void* d_out, int out_size, void* d_ws, size_t ws_size,
                              hipStream_t stream) {
    (void)in_sizes; (void)n_in; (void)d_ws; (void)ws_size; (void)out_size;
    const float* inp = (const float*)d_in[0];
    const float* kw  = (const float*)d_in[1];
    float* out = (float*)d_out;

    // Closed-form LIF scan with I = 1 (double precision; exact by linearity).
    double v = 0.0;
    v = v + (3000.0 * 1.0 - v) / 30000.0 * 0.01;   // = 0.001
    double vt = v;
    for (int i = 0; i < 999; ++i) {
        v  = v + (3000.0 - v) / 30000.0 * 0.01;
        vt = (v + vt) / 1000.0;
    }
    float c = (float)vt;   // ~0.99983...

    dim3 block(256, 1, 1);
    dim3 grid(16, 64, 1);  // 16 slabs x 64 batches = 1024 blocks, all co-resident
    hipLaunchKernelGGL(snn_conv_dbuf_kernel, grid, block, 0, stream,
                       inp, kw, out, c);
}

// Round 7
// 114.590 us; speedup vs baseline: 1.0273x; 1.0273x over previous
//
#include <hip/hip_runtime.h>

// out[b,i,j] = conv3x3_valid(inp, c*k)[b,i,j]
// c = vt(I=1) from the LIF scan (linear in I; spike/clamp provably inactive
// since I < 9 < 14 for all 1000 steps). c folded into the taps.
//
// R7: software-pipelined vertical walk, fine-grained vmcnt + RAW s_barrier
// (no __syncthreads -> no vmcnt(0) drain of in-flight prefetch/stores).
// Block = 32-row output slab. Input staged in 4-row stages (8192 B) into a
// 5-slot circular LDS buffer via async global_load_lds width=16. Rolling
// vertical h-sums (a2/a1) carry ACROSS stages -> no halo re-staging
// (9 stages of 4 rows = 36 rows read per 32 output rows, 1.125x).
// Body t: s_waitcnt vmcnt(6) leaves the 2-3 newest stage-pairs + all stores
// outstanding; stage t's pair is provably older than >=6 ops (pairs t+1,t+2
// = 4, plus >=4 stores/body), so it is drained -- store-count independent.
// LDS 5*8192 = 40960 B exactly -> 4 blocks/CU; grid 16x64 = 1024 blocks =
// fully co-resident. Thread owns 2 cols (tid*2); lane 255 computes garbage
// halo, never stores.

#define NBUF 5
#define STGF 2048   // floats per stage = 4 rows * 512

__device__ static inline void async_copy16(const float* gsrc, float* ldst) {
    __builtin_amdgcn_global_load_lds(
        (const __attribute__((address_space(1))) void*)gsrc,
        (__attribute__((address_space(3))) void*)ldst, 16, 0, 0);
}

__global__ __launch_bounds__(256) void snn_conv_pipe_kernel(
    const float* __restrict__ inp, const float* __restrict__ kw,
    float* __restrict__ out, float c)
{
    __shared__ float tile[NBUF * STGF];          // 40960 B

    const int tid = threadIdx.x;
    const int b   = blockIdx.y;
    const int ib0 = blockIdx.x * 32;             // first output/input row of slab

    const float* gbase = inp + (size_t)b * 262144;   // 512*512

    // stage s holds input rows ib0+4s .. ib0+4s+3 (global addr clamped; the
    // clamped rows are garbage whose outputs are discarded by the orow guard)
#define STAGE(s)                                                              \
    {   const int _gf0 = (ib0 + 4*(s)) * 512;                                 \
        const int _l0  = ((s) % NBUF) * STGF;                                 \
        async_copy16(gbase + min(_gf0 + tid*4,        262140),                \
                     &tile[_l0 + tid*4]);                                     \
        async_copy16(gbase + min(_gf0 + 1024 + tid*4, 262140),                \
                     &tile[_l0 + 1024 + tid*4]); }

    STAGE(0) STAGE(1) STAGE(2) STAGE(3)          // 8 DMA insts in flight

    const float k00 = kw[0]*c, k01 = kw[1]*c, k02 = kw[2]*c;
    const float k10 = kw[3]*c, k11 = kw[4]*c, k12 = kw[5]*c;
    const float k20 = kw[6]*c, k21 = kw[7]*c, k22 = kw[8]*c;

    // drain stages 0,1 (leave 2,3 flying), then block-wide raw barrier
    asm volatile("s_waitcnt vmcnt(4)" ::: "memory");
    __builtin_amdgcn_s_barrier();

    const int  j  = tid * 2;                     // cols j, j+1
    const bool st = (tid < 255);                 // tid 255 (cols 510,511): no store
    const int  j2 = st ? j + 2 : j;              // halo read, clamped in-bounds

    float x0, x1, x2, x3;
#define LOADX(off)                                                            \
    {   float2 _a = *(const float2*)(&tile[(off) + j]);                       \
        float2 _b = *(const float2*)(&tile[(off) + j2]);                      \
        x0 = _a.x; x1 = _a.y; x2 = _b.x; x3 = _b.y; }

    float a2_0, a2_1, a1_0, a1_1;
    LOADX(0);                                    // row ib0   (stage 0, rin 0)
    a2_0 = k00*x0 + k01*x1 + k02*x2;
    a2_1 = k00*x1 + k01*x2 + k02*x3;
    LOADX(512);                                  // row ib0+1 (stage 0, rin 1)
    a1_0 = k00*x0 + k01*x1 + k02*x2;  a2_0 += k10*x0 + k11*x1 + k12*x2;
    a1_1 = k00*x1 + k01*x2 + k02*x3;  a2_1 += k10*x1 + k11*x2 + k12*x3;

    float* obase = out + (size_t)b * 260100;     // 510*510

#pragma unroll
    for (int t = 1; t <= 8; ++t) {
        // stage t's DMA pair is older than >=6 ops (stage t+1,t+2 pairs +
        // stores) -> vmcnt(6) guarantees it has landed; stores + newest
        // prefetches stay in flight across the raw barrier.
        asm volatile("s_waitcnt vmcnt(6)" ::: "memory");
        __builtin_amdgcn_s_barrier();

#pragma unroll
        for (int r = 0; r < 4; ++r) {
            const int g   = 4*t + r - 2;                     // block-rel input row
            const int off = ((g >> 2) % NBUF) * STGF + (g & 3) * 512;
            LOADX(off);
            const float o0 = a2_0 + k20*x0 + k21*x1 + k22*x2;
            const float o1 = a2_1 + k20*x1 + k21*x2 + k22*x3;

            const int orow = ib0 + 4*(t - 1) + r;
            if (st && orow < 510)                            // tail rows 510,511 skipped
                *(float2*)(obase + (size_t)orow * 510 + j) = make_float2(o0, o1);

            a2_0 = a1_0 + k10*x0 + k11*x1 + k12*x2;
            a2_1 = a1_1 + k10*x1 + k11*x2 + k12*x3;
            a1_0 = k00*x0 + k01*x1 + k02*x2;
            a1_1 = k00*x1 + k01*x2 + k02*x3;
        }
        if (t + 3 <= 8) STAGE(t + 3)             // 3-stage lookahead, issued last
    }
#undef LOADX
#undef STAGE
}

extern "C" void kernel_launch(void* const* d_in, const int* in_sizes, int n_in,
                              void* d_out, int out_size, void* d_ws, size_t ws_size,
                              hipStream_t stream) {
    (void)in_sizes; (void)n_in; (void)d_ws; (void)ws_size; (void)out_size;
    const float* inp = (const float*)d_in[0];
    const float* kw  = (const float*)d_in[1];
    float* out = (float*)d_out;

    // Closed-form LIF scan with I = 1 (double precision; exact by linearity).
    double v = 0.0;
    v = v + (3000.0 * 1.0 - v) / 30000.0 * 0.01;   // = 0.001
    double vt = v;
    for (int i = 0; i < 999; ++i) {
        v  = v + (3000.0 - v) / 30000.0 * 0.01;
        vt = (v + vt) / 1000.0;
    }
    float c = (float)vt;   // ~0.99983...

    dim3 block(256, 1, 1);
    dim3 grid(16, 64, 1);  // 16 slabs x 64 batches = 1024 blocks, all co-resident
    hipLaunchKernelGGL(snn_conv_pipe_kernel, grid, block, 0, stream,
                       inp, kw, out, c);
}